// Round 8
// baseline (723.066 us; speedup 1.0000x reference)
//
#include <hip/hip_runtime.h>

#define NNODES 100000
#define MPAD   100032          // 1563 * 64
#define NEDGES 1600000
#define NGRAPHS 2000
#define HID 256
#define OUTD 128
#define NCLS 60
#define BN_EPS 1e-5f
#define NROWBLK 1563   // ceil(NNODES/64)
#define NSCANBLK 98    // ceil(NNODES/1024)
#define REDBLK 32
#define DPAD 16        // histogram counter stride (64B per counter)

typedef __attribute__((ext_vector_type(8))) short bf16x8;
typedef __attribute__((ext_vector_type(4))) float f32x4;

__device__ __forceinline__ float b2f(unsigned short b) {
    unsigned int u = ((unsigned int)b) << 16;
    return __builtin_bit_cast(float, u);
}
__device__ __forceinline__ unsigned short f2b(float f) {
    unsigned int u = __builtin_bit_cast(unsigned int, f);
    u = (u + 0x7FFFu + ((u >> 16) & 1u)) >> 16;     // RNE
    return (unsigned short)u;
}

// ---------------- utility: vectorized zero ----------------
__global__ void k_zero4(int4* __restrict__ p, int n4) {
    int i = blockIdx.x * blockDim.x + threadIdx.x;
    if (i < n4) p[i] = make_int4(0, 0, 0, 0);
}

// ---------------- degrees + local position; padded counters, 4 edges/thread --------
__global__ __launch_bounds__(256) void k_deg2(
        const int* __restrict__ src, const int* __restrict__ dst,
        int* __restrict__ dout, int* __restrict__ din, int* __restrict__ lpos) {
    int t = blockIdx.x * 256 + threadIdx.x;          // 400128 threads
#pragma unroll
    for (int j = 0; j < 4; ++j) {
        int e = t + j * 400128;
        if (e < NEDGES) {
            atomicAdd(&dout[src[e] * DPAD], 1);
            lpos[e] = atomicAdd(&din[dst[e] * DPAD], 1);
        }
    }
}

// ---------------- block sums of din + fused isqrt of both degree arrays ----------
__global__ void k_blk_sum(const int* __restrict__ din, const int* __restrict__ dout,
                          int* __restrict__ bsum, float* __restrict__ dos,
                          float* __restrict__ dis) {
    __shared__ int red[256];
    int blk = blockIdx.x, tid = threadIdx.x;
    int base = blk * 1024;
    int s = 0;
#pragma unroll
    for (int j = 0; j < 4; ++j) {
        int i = base + tid + j * 256;
        if (i < NNODES) {
            int b = din[i * DPAD];
            int a = dout[i * DPAD];
            s += b;
            dos[i] = a > 0 ? 1.0f / sqrtf((float)a) : 0.0f;
            dis[i] = b > 0 ? 1.0f / sqrtf((float)b) : 0.0f;
        }
    }
    red[tid] = s;
    __syncthreads();
    for (int off = 128; off > 0; off >>= 1) {
        if (tid < off) red[tid] += red[tid + off];
        __syncthreads();
    }
    if (tid == 0) bsum[blk] = red[0];
}

__global__ void k_scan_bsum(int* __restrict__ bsum) {
    if (threadIdx.x == 0) {
        int acc = 0;
        for (int i = 0; i < NSCANBLK; ++i) { int v = bsum[i]; bsum[i] = acc; acc += v; }
    }
}

__global__ void k_scan_local(const int* __restrict__ deg, const int* __restrict__ bsum,
                             int* __restrict__ row_ptr) {
    __shared__ int buf[1024];
    int blk = blockIdx.x, tid = threadIdx.x;
    int i = blk * 1024 + tid;
    int v = (i < NNODES) ? deg[i * DPAD] : 0;
    buf[tid] = v;
    __syncthreads();
    for (int off = 1; off < 1024; off <<= 1) {
        int t = (tid >= off) ? buf[tid - off] : 0;
        __syncthreads();
        buf[tid] += t;
        __syncthreads();
    }
    int inc = buf[tid] + bsum[blk];
    if (i < NNODES) row_ptr[i + 1] = inc;
    if (i == 0) row_ptr[0] = 0;
}

// ---------------- atomic-free edge placement ----------------
__global__ void k_place(const int* __restrict__ src, const int* __restrict__ dst,
                        const int* __restrict__ lpos, const int* __restrict__ row_ptr,
                        int* __restrict__ csr_e) {
    int e = blockIdx.x * blockDim.x + threadIdx.x;
    if (e < NEDGES) csr_e[row_ptr[dst[e]] + lpos[e]] = src[e];
}

// ---------------- fused prep: nf7 | weight-convert x3 | M1/v1 ----------------------
// blocks 0..390: nf7[n] = [nf*w (6), w, 0];  391..1030: bf16 W^T converts;
// 1031..1037: M1 = Wemb@Wc1 (6x256) and v1 = bemb@Wc1.
__global__ void k_prep(const float* __restrict__ nf, const float* __restrict__ dos,
                       float* __restrict__ nf7,
                       const float* __restrict__ W2, const float* __restrict__ Wc2,
                       const float* __restrict__ W3, unsigned short* __restrict__ Wt2,
                       unsigned short* __restrict__ Wtc2, unsigned short* __restrict__ Wt3,
                       const float* __restrict__ Wemb, const float* __restrict__ bemb,
                       const float* __restrict__ Wc1, float* __restrict__ M1,
                       float* __restrict__ v1) {
    int blk = blockIdx.x, tid = threadIdx.x;
    if (blk < 391) {
        int n = blk * 256 + tid;
        if (n < NNODES) {
            float w = dos[n];
            const float* p = nf + (size_t)n * 6;
            float4 lo = {p[0] * w, p[1] * w, p[2] * w, p[3] * w};
            float4 hi = {p[4] * w, p[5] * w, w, 0.f};
            float4* o = (float4*)(nf7 + (size_t)n * 8);
            o[0] = lo; o[1] = hi;
        }
    } else if (blk < 1031) {
        int idx = (blk - 391) * 256 + tid;
        if (idx < 65536) {
            int n = idx >> 8, k = idx & 255;
            Wt2[idx] = f2b(W2[k * 256 + n]);
        } else if (idx < 131072) {
            int j = idx - 65536;
            int n = j >> 8, k = j & 255;
            Wtc2[j] = f2b(Wc2[k * 256 + n]);
        } else {
            int j = idx - 131072;
            int n = j >> 8, k = j & 255;
            Wt3[j] = f2b(W3[k * 128 + n]);
        }
    } else {
        int bi = blk - 1031;
        int c = tid;
        float acc = 0.f;
        if (bi < 6) {
            for (int k = 0; k < HID; ++k) acc = fmaf(Wemb[bi * HID + k], Wc1[k * HID + c], acc);
            M1[bi * HID + c] = acc;
        } else {
            for (int k = 0; k < HID; ++k) acc = fmaf(bemb[k], Wc1[k * HID + c], acc);
            v1[c] = acc;
        }
    }
}

// ---------------- 7-dim edge aggregation (collapsed layer-1 conv, pre-scaled) -------
__global__ void k_agg6(const int* __restrict__ row_ptr, const int* __restrict__ csr_e,
                       const float* __restrict__ nf7, float* __restrict__ t7) {
    int n = blockIdx.x * blockDim.x + threadIdx.x;
    if (n >= NNODES) return;
    float a0 = 0, a1 = 0, a2 = 0, a3 = 0, a4 = 0, a5 = 0, a6 = 0;
    int s = row_ptr[n], e = row_ptr[n + 1];
    int i = s;
    for (; i + 2 <= e; i += 2) {
        const float4* p0 = (const float4*)(nf7 + (size_t)csr_e[i] * 8);
        const float4* p1 = (const float4*)(nf7 + (size_t)csr_e[i + 1] * 8);
        float4 l0 = p0[0], h0 = p0[1], l1 = p1[0], h1 = p1[1];
        a0 += l0.x; a1 += l0.y; a2 += l0.z; a3 += l0.w; a4 += h0.x; a5 += h0.y; a6 += h0.z;
        a0 += l1.x; a1 += l1.y; a2 += l1.z; a3 += l1.w; a4 += h1.x; a5 += h1.y; a6 += h1.z;
    }
    if (i < e) {
        const float4* p0 = (const float4*)(nf7 + (size_t)csr_e[i] * 8);
        float4 l0 = p0[0], h0 = p0[1];
        a0 += l0.x; a1 += l0.y; a2 += l0.z; a3 += l0.w; a4 += h0.x; a5 += h0.y; a6 += h0.z;
    }
    float4* o = (float4*)(t7 + (size_t)n * 8);
    o[0] = make_float4(a0, a1, a2, a3);
    o[1] = make_float4(a4, a5, a6, 0.f);
}

// ---------------- fused layer 1 -> bf16 h_pre1 + fp32 BN partials ----------------
__global__ __launch_bounds__(256) void k_layer1(
    const float* __restrict__ nf, const float* __restrict__ Wemb, const float* __restrict__ bemb,
    const float* __restrict__ M1, const float* __restrict__ v1, const float* __restrict__ bc1,
    const float* __restrict__ t7, const float* __restrict__ dis,
    unsigned short* __restrict__ H, float* __restrict__ psum, float* __restrict__ psq) {
    __shared__ float s_nf[64][6];
    __shared__ float s_t7[64][8];
    __shared__ float s_r[64];
    int blk = blockIdx.x;
    int n0 = blk * 64;
    int tid = threadIdx.x;
    for (int t = tid; t < 384; t += 256) {
        int nl = t / 6, i = t % 6;
        int n = n0 + nl;
        s_nf[nl][i] = (n < NNODES) ? nf[(size_t)n * 6 + i] : 0.f;
    }
    if (tid < 128) {   // 64 rows x 8 floats = 128 float4; guard reads to NNODES rows
        int n = n0 + tid / 2;
        if (n < NNODES)
            ((float4*)s_t7)[tid] = ((const float4*)(t7 + (size_t)n0 * 8))[tid];
        else
            ((float4*)s_t7)[tid] = make_float4(0.f, 0.f, 0.f, 0.f);
    }
    if (tid < 64) {
        int n = n0 + tid;
        s_r[tid] = (n < NNODES) ? dis[n] : 0.f;
    }
    int c = tid;
    float wc[6], mc[6];
#pragma unroll
    for (int i = 0; i < 6; ++i) { wc[i] = Wemb[i * HID + c]; mc[i] = M1[i * HID + c]; }
    float v1c = v1[c];
    float bsum = bemb[c] + bc1[c];
    __syncthreads();
    float ps = 0.f, pq = 0.f;
    int nmax = min(64, NNODES - n0);
    for (int nl = 0; nl < nmax; ++nl) {
        float nfd = 0.f, td = 0.f;
#pragma unroll
        for (int i = 0; i < 6; ++i) {
            nfd = fmaf(s_nf[nl][i], wc[i], nfd);
            td = fmaf(s_t7[nl][i], mc[i], td);
        }
        float val = nfd + s_r[nl] * (td + s_t7[nl][6] * v1c) + bsum;
        H[(size_t)(n0 + nl) * HID + c] = f2b(val);
        ps += val;
        pq = fmaf(val, val, pq);
    }
    for (int nl = nmax; nl < 64; ++nl) H[(size_t)(n0 + nl) * HID + c] = 0;  // zero pad rows
    psum[blk * HID + c] = ps;
    psq[blk * HID + c] = pq;
}

// ---------------- BN two-stage reduce -> scale/shift ----------------
__global__ void k_bn_part(const float* __restrict__ psum, const float* __restrict__ psq,
                          double* __restrict__ tmp) {
    int c = threadIdx.x;
    int s = blockIdx.x;
    double a = 0.0, b = 0.0;
    for (int bb = s; bb < NROWBLK; bb += REDBLK) {
        a += psum[bb * HID + c];
        b += psq[bb * HID + c];
    }
    tmp[s * HID + c] = a;
    tmp[(REDBLK + s) * HID + c] = b;
}

__global__ void k_bn_final(const double* __restrict__ tmp, const float* __restrict__ g,
                           const float* __restrict__ be, float* __restrict__ scale,
                           float* __restrict__ shift) {
    int c = threadIdx.x;
    double s = 0.0, q = 0.0;
    for (int i = 0; i < REDBLK; ++i) { s += tmp[i * HID + c]; q += tmp[(REDBLK + i) * HID + c]; }
    double mu = s / (double)NNODES;
    double var = q / (double)NNODES - mu * mu;
    if (var < 0.0) var = 0.0;
    double inv = 1.0 / sqrt(var + (double)BN_EPS);
    float sc = (float)((double)g[c] * inv);
    scale[c] = sc;
    shift[c] = be[c] - (float)mu * sc;
}

// ================= bf16 MFMA GEMM, A-panel reused across all column blocks =========
// RS: multiply output rows by rs[row] (folds dout^-1/2 into h2 for the gather pass)
template <int NC, bool ATRANS, bool XEPI, bool PART, bool OUTF32, bool RS>
__global__ __launch_bounds__(256, 2) void k_mgemm(
    const unsigned short* __restrict__ A, const unsigned short* __restrict__ Bt,
    const float* __restrict__ bias,
    const float* __restrict__ scale, const float* __restrict__ shift,
    const float* __restrict__ nf, const float* __restrict__ Wemb, const float* __restrict__ bemb,
    const float* __restrict__ rs,
    unsigned short* __restrict__ Cb, float* __restrict__ Cf,
    float* __restrict__ psum, float* __restrict__ psq) {
    __shared__ unsigned short As[64 * 256];
    __shared__ unsigned short Bs[64 * 256];
    __shared__ float sSc[HID];
    __shared__ float sSh[HID];
    __shared__ float sNf[64][6];
    __shared__ float sXW[6][HID];
    __shared__ float sRs[64];
    __shared__ float redS[2][64];
    __shared__ float redQ[2][64];

    int tid = threadIdx.x;
    int rb = blockIdx.x;
    int row0 = rb * 64;

    if (ATRANS) { sSc[tid] = scale[tid]; sSh[tid] = shift[tid]; }
    if (RS && tid < 64) {
        int n = row0 + tid;
        sRs[tid] = (n < NNODES) ? rs[n] : 0.f;
    }
    if (XEPI) {
        for (int t = tid; t < 6 * NC; t += 256) {
            int i = t / NC, cl = t % NC;
            sXW[i][cl] = Wemb[i * HID + cl];
        }
        if (tid < 64) {
            int n = row0 + tid;
#pragma unroll
            for (int i = 0; i < 6; ++i) sNf[tid][i] = (n < NNODES) ? nf[(size_t)n * 6 + i] : 0.f;
        }
    }
    if (ATRANS) __syncthreads();   // sSc/sSh consumed during A staging

    // ---- stage A tile 64x256 bf16 once ----
#pragma unroll
    for (int i = 0; i < 8; ++i) {
        int g = i * 256 + tid;
        int row = g >> 5, kc = g & 31;
        uint4 v = *(const uint4*)(A + (size_t)(row0 + row) * 256 + kc * 8);
        if (ATRANS) {
            unsigned int w[4] = {v.x, v.y, v.z, v.w};
#pragma unroll
            for (int q = 0; q < 4; ++q) {
                int k0 = kc * 8 + q * 2;
                float f0 = b2f((unsigned short)(w[q] & 0xffffu));
                float f1 = b2f((unsigned short)(w[q] >> 16));
                f0 = fmaxf(fmaf(f0, sSc[k0], sSh[k0]), 0.f);
                f1 = fmaxf(fmaf(f1, sSc[k0 + 1], sSh[k0 + 1]), 0.f);
                w[q] = (unsigned int)f2b(f0) | ((unsigned int)f2b(f1) << 16);
            }
            v.x = w[0]; v.y = w[1]; v.z = w[2]; v.w = w[3];
        }
        int pkc = kc ^ (row & 7);
        *(uint4*)(&As[row * 256 + pkc * 8]) = v;
    }

    int w = tid >> 6, lane = tid & 63;
    int wm = w >> 1, wn = w & 1;            // 2x2 wave grid, each wave 32x32
    int lrow = lane & 15, lk = lane >> 4;

    for (int cb = 0; cb < NC / 64; ++cb) {
        int c0 = cb * 64;
        if (cb) __syncthreads();
        // ---- stage B^T tile 64x256 bf16 ----
#pragma unroll
        for (int i = 0; i < 8; ++i) {
            int g = i * 256 + tid;
            int row = g >> 5, kc = g & 31;
            uint4 v = *(const uint4*)(Bt + (size_t)(c0 + row) * 256 + kc * 8);
            int pkc = kc ^ (row & 7);
            *(uint4*)(&Bs[row * 256 + pkc * 8]) = v;
        }
        __syncthreads();

        f32x4 acc[2][2] = {};
#pragma unroll
        for (int ks = 0; ks < 8; ++ks) {
            bf16x8 af[2], bfr[2];
#pragma unroll
            for (int fm = 0; fm < 2; ++fm) {
                int r = wm * 32 + fm * 16 + lrow;
                int kc = ks * 4 + lk;
                af[fm] = *(const bf16x8*)(&As[r * 256 + (kc ^ (r & 7)) * 8]);
            }
#pragma unroll
            for (int fn = 0; fn < 2; ++fn) {
                int r = wn * 32 + fn * 16 + lrow;
                int kc = ks * 4 + lk;
                bfr[fn] = *(const bf16x8*)(&Bs[r * 256 + (kc ^ (r & 7)) * 8]);
            }
#pragma unroll
            for (int fm = 0; fm < 2; ++fm)
#pragma unroll
                for (int fn = 0; fn < 2; ++fn)
                    acc[fm][fn] = __builtin_amdgcn_mfma_f32_16x16x32_bf16(af[fm], bfr[fn], acc[fm][fn], 0, 0, 0);
        }

        // ---- epilogue (C/D layout: col=lane&15, row=(lane>>4)*4+reg) ----
        float pS[2] = {0.f, 0.f}, pQ[2] = {0.f, 0.f};
#pragma unroll
        for (int fn = 0; fn < 2; ++fn) {
            int cl = wn * 32 + fn * 16 + lrow;
            int gc = c0 + cl;
            float bv = bias[gc];
            if (XEPI) bv += bemb[gc];
#pragma unroll
            for (int fm = 0; fm < 2; ++fm) {
#pragma unroll
                for (int r = 0; r < 4; ++r) {
                    int rl = wm * 32 + fm * 16 + lk * 4 + r;
                    int gr = row0 + rl;
                    float val = acc[fm][fn][r] + bv;
                    if (XEPI) {
#pragma unroll
                        for (int l = 0; l < 6; ++l) val = fmaf(sNf[rl][l], sXW[l][gc], val);
                    }
                    if (RS) val *= sRs[rl];
                    if (gr < NNODES) {
                        if (OUTF32) Cf[(size_t)gr * NC + gc] = val;
                        else        Cb[(size_t)gr * NC + gc] = f2b(val);
                        if (PART) { pS[fn] += val; pQ[fn] = fmaf(val, val, pQ[fn]); }
                    }
                }
            }
        }
        if (PART) {
#pragma unroll
            for (int fn = 0; fn < 2; ++fn) {
                float s = pS[fn], q = pQ[fn];
                s += __shfl_xor(s, 16); s += __shfl_xor(s, 32);
                q += __shfl_xor(q, 16); q += __shfl_xor(q, 32);
                if (lk == 0) {
                    int cl = wn * 32 + fn * 16 + lrow;
                    redS[wm][cl] = s;
                    redQ[wm][cl] = q;
                }
            }
            __syncthreads();
            if (tid < 64) {
                psum[(size_t)rb * HID + c0 + tid] = redS[0][tid] + redS[1][tid];
                psq [(size_t)rb * HID + c0 + tid] = redQ[0][tid] + redQ[1][tid];
            }
        }
    }
}

// ---------------- bf16 conv aggregation: weights pre-folded, plain row sums ---------
#define ADD8(vv) { \
    a[0] += b2f((unsigned short)(vv.x & 0xffffu)); \
    a[1] += b2f((unsigned short)(vv.x >> 16)); \
    a[2] += b2f((unsigned short)(vv.y & 0xffffu)); \
    a[3] += b2f((unsigned short)(vv.y >> 16)); \
    a[4] += b2f((unsigned short)(vv.z & 0xffffu)); \
    a[5] += b2f((unsigned short)(vv.z >> 16)); \
    a[6] += b2f((unsigned short)(vv.w & 0xffffu)); \
    a[7] += b2f((unsigned short)(vv.w >> 16)); }

__global__ __launch_bounds__(256) void k_agg(const int* __restrict__ row_ptr,
                                             const int* __restrict__ csr_e,
                                             const unsigned short* __restrict__ X,
                                             const float* __restrict__ dis,
                                             unsigned short* __restrict__ out) {
    int wid = threadIdx.x >> 6, lane = threadIdx.x & 63;
    int half = lane >> 5, l32 = lane & 31;
    int n = blockIdx.x * 4 + wid;
    if (n >= NNODES) return;
    int s = row_ptr[n], e = row_ptr[n + 1];
    float a[8] = {0.f, 0.f, 0.f, 0.f, 0.f, 0.f, 0.f, 0.f};
    int i = s;
    for (; i + 8 <= e; i += 8) {
        int s0 = csr_e[i + half];
        int s1 = csr_e[i + 2 + half];
        int s2 = csr_e[i + 4 + half];
        int s3 = csr_e[i + 6 + half];
        uint4 v0 = ((const uint4*)(X + (size_t)s0 * HID))[l32];
        uint4 v1 = ((const uint4*)(X + (size_t)s1 * HID))[l32];
        uint4 v2 = ((const uint4*)(X + (size_t)s2 * HID))[l32];
        uint4 v3 = ((const uint4*)(X + (size_t)s3 * HID))[l32];
        ADD8(v0) ADD8(v1) ADD8(v2) ADD8(v3)
    }
    for (; i + 2 <= e; i += 2) {
        int s0 = csr_e[i + half];
        uint4 v0 = ((const uint4*)(X + (size_t)s0 * HID))[l32];
        ADD8(v0)
    }
    if (i < e && half == 0) {       // odd leftover edge: half 0 only
        int s0 = csr_e[i];
        uint4 v0 = ((const uint4*)(X + (size_t)s0 * HID))[l32];
        ADD8(v0)
    }
#pragma unroll
    for (int j = 0; j < 8; ++j) a[j] += __shfl_xor(a[j], 32);
    if (half == 0) {
        float r = dis[n];
        uint4 o;
        o.x = (unsigned)f2b(a[0] * r) | ((unsigned)f2b(a[1] * r) << 16);
        o.y = (unsigned)f2b(a[2] * r) | ((unsigned)f2b(a[3] * r) << 16);
        o.z = (unsigned)f2b(a[4] * r) | ((unsigned)f2b(a[5] * r) << 16);
        o.w = (unsigned)f2b(a[6] * r) | ((unsigned)f2b(a[7] * r) << 16);
        ((uint4*)(out + (size_t)n * HID))[l32] = o;
    }
}

// ---------------- graph mean (sorted graph_ids, binary search) + classifier --------
__global__ __launch_bounds__(128) void k_mean_label(const float* __restrict__ Hout,
                                                    const int* __restrict__ gids,
                                                    const float* __restrict__ Wcls,
                                                    const float* __restrict__ bcls,
                                                    float* __restrict__ lab) {
    int g = blockIdx.x;
    int c = threadIdx.x;
    int lo = 0, hi = NNODES;
    while (lo < hi) { int mid = (lo + hi) >> 1; if (gids[mid] < g) lo = mid + 1; else hi = mid; }
    int s = lo;
    hi = NNODES;
    while (lo < hi) { int mid = (lo + hi) >> 1; if (gids[mid] < g + 1) lo = mid + 1; else hi = mid; }
    int e = lo;
    float acc = 0.f;
    for (int n = s; n < e; ++n) acc += Hout[(size_t)n * OUTD + c];
    int cnt = e - s;
    float y = acc / (float)max(cnt, 1);
    __shared__ float ys[OUTD];
    ys[c] = y;
    __syncthreads();
    if (c < NCLS) {
        float a = bcls[c];
        for (int k = 0; k < OUTD; ++k) a = fmaf(ys[k], Wcls[k * NCLS + c], a);
        lab[(size_t)g * NCLS + c] = a;
    }
}

// ---------------- host ----------------
extern "C" void kernel_launch(void* const* d_in, const int* in_sizes, int n_in,
                              void* d_out, int out_size, void* d_ws, size_t ws_size,
                              hipStream_t stream) {
    const float* nf   = (const float*)d_in[0];
    const int*   src  = (const int*)d_in[1];
    const int*   dst  = (const int*)d_in[2];
    const int*   gids = (const int*)d_in[3];
    const float* Wemb = (const float*)d_in[4];
    const float* bemb = (const float*)d_in[5];
    const float* Wc1  = (const float*)d_in[6];
    const float* bc1  = (const float*)d_in[7];
    const float* g1   = (const float*)d_in[8];
    const float* be1  = (const float*)d_in[9];
    const float* W2   = (const float*)d_in[10];
    const float* b2   = (const float*)d_in[11];
    const float* Wc2  = (const float*)d_in[12];
    const float* bc2  = (const float*)d_in[13];
    const float* g2   = (const float*)d_in[14];
    const float* be2  = (const float*)d_in[15];
    const float* W3   = (const float*)d_in[16];
    const float* b3   = (const float*)d_in[17];
    const float* Wcls = (const float*)d_in[18];
    const float* bcls = (const float*)d_in[19];

    float* out_h   = (float*)d_out;                 // [N, 128] fp32
    float* out_lab = out_h + (size_t)NNODES * OUTD; // [G, 60]

    // workspace bump allocator (floats, 256B granularity)
    float* ws = (float*)d_ws;
    size_t off = 0;
    auto take = [&](size_t n) { float* p = ws + off; off += (n + 63) & ~(size_t)63; return p; };
    unsigned short* actA = (unsigned short*)take((size_t)MPAD * HID / 2);  // bf16 [MPAD][256]
    unsigned short* actB = (unsigned short*)take((size_t)MPAD * HID / 2);  // bf16 [MPAD][256]
    unsigned short* Wt2  = (unsigned short*)take(HID * HID / 2);
    unsigned short* Wtc2 = (unsigned short*)take(HID * HID / 2);
    unsigned short* Wt3  = (unsigned short*)take(OUTD * HID / 2);
    float* dout_is = take(NNODES);
    float* din_is  = take(NNODES);
    int*   row_ptr = (int*)take(NNODES + 1);
    float* lpos_t7 = take(NEDGES);                 // lpos (steps 2-4), then t7 (6-7)
    int*   csr_e   = (int*)take(NEDGES);
    float* nf7_ps  = take(800320);                 // nf7 (5-6), then psum+psq (7+)
    float* M1      = take(6 * HID);
    float* v1      = take(HID);
    float* scale1  = take(HID);
    float* shift1  = take(HID);
    float* scale2  = take(HID);
    float* shift2  = take(HID);
    int*   bsum    = (int*)take(128);
    double* bn_tmp = (double*)take(2 * 2 * REDBLK * HID);

    // aliases (lifetimes verified: degs dead before actA written at step 7;
    // lpos dead after step 4, t7 written step 6; nf7 dead after step 6, psum step 7)
    int*   deg_out = (int*)actA;                   // [100032*DPAD] ints = 6.4MB
    int*   deg_in  = deg_out + 100032 * DPAD;      // 6.4MB
    int*   lpos    = (int*)lpos_t7;
    float* t7      = lpos_t7;
    float* nf7     = nf7_ps;
    float* psum    = nf7_ps;
    float* psq     = nf7_ps + 400128;

    // 1. zero padded degree arrays (2 x 100032 x DPAD ints, int4-vectorized)
    k_zero4<<<(2 * 100032 * DPAD / 4 + 255) / 256, 256, 0, stream>>>(
        (int4*)deg_out, 2 * 100032 * DPAD / 4);
    // 2. degrees + local positions (padded counters, 4 edges/thread)
    k_deg2<<<1563, 256, 0, stream>>>(src, dst, deg_out, deg_in, lpos);
    // 3. block sums + fused isqrt
    k_blk_sum<<<NSCANBLK, 256, 0, stream>>>(deg_in, deg_out, bsum, dout_is, din_is);
    k_scan_bsum<<<1, 64, 0, stream>>>(bsum);
    k_scan_local<<<NSCANBLK, 1024, 0, stream>>>(deg_in, bsum, row_ptr);
    // 4. atomic-free placement
    k_place<<<(NEDGES + 255) / 256, 256, 0, stream>>>(src, dst, lpos, row_ptr, csr_e);
    // 5. fused prep: nf7 + weight converts + M1/v1
    k_prep<<<1038, 256, 0, stream>>>(nf, dout_is, nf7, W2, Wc2, W3, Wt2, Wtc2, Wt3,
                                     Wemb, bemb, Wc1, M1, v1);
    // 6. 7-dim aggregation -> t7 (overwrites lpos)
    k_agg6<<<(NNODES + 255) / 256, 256, 0, stream>>>(row_ptr, csr_e, nf7, t7);
    // 7. fused layer 1 -> actA (h_pre1 bf16) + BN1 partials (psum/psq overwrite nf7)
    k_layer1<<<NROWBLK, 256, 0, stream>>>(nf, Wemb, bemb, M1, v1, bc1, t7, din_is,
                                          actA, psum, psq);
    // 8. BN1 scale/shift
    k_bn_part<<<REDBLK, 256, 0, stream>>>(psum, psq, bn_tmp);
    k_bn_final<<<1, 256, 0, stream>>>(bn_tmp, g1, be1, scale1, shift1);
    // 9. h2 = (relu(bn1(h_pre1)) @ W2 + b2) * dout^-1/2[row] -> actB (bf16)
    k_mgemm<HID, true, false, false, false, true><<<NROWBLK, 256, 0, stream>>>(
        actA, Wt2, b2, scale1, shift1, nullptr, nullptr, nullptr, dout_is,
        actB, nullptr, nullptr, nullptr);
    // 10. A2 = dis * row-sum gather of actB -> actA (bf16)
    k_agg<<<NNODES / 4, 256, 0, stream>>>(row_ptr, csr_e, actB, din_is, actA);
    // 11. h_pre2 = x + A2 @ Wc2 + bc2 -> actB (bf16) + BN2 partials
    k_mgemm<HID, false, true, true, false, false><<<NROWBLK, 256, 0, stream>>>(
        actA, Wtc2, bc2, nullptr, nullptr, nf, Wemb, bemb, nullptr,
        actB, nullptr, psum, psq);
    // 12. BN2 scale/shift
    k_bn_part<<<REDBLK, 256, 0, stream>>>(psum, psq, bn_tmp);
    k_bn_final<<<1, 256, 0, stream>>>(bn_tmp, g2, be2, scale2, shift2);
    // 13. h_out = relu(bn2(h_pre2)) @ W3 + b3 -> d_out fp32
    k_mgemm<OUTD, true, false, false, true, false><<<NROWBLK, 256, 0, stream>>>(
        actB, Wt3, b3, scale2, shift2, nullptr, nullptr, nullptr, nullptr,
        nullptr, out_h, nullptr, nullptr);
    // 14. graph mean + classifier
    k_mean_label<<<NGRAPHS, OUTD, 0, stream>>>(out_h, gids, Wcls, bcls, out_lab);
}

// Round 9
// 683.456 us; speedup vs baseline: 1.0580x; 1.0580x over previous
//
#include <hip/hip_runtime.h>

#define NNODES 100000
#define MPAD   100032          // 1563 * 64
#define NEDGES 1600000
#define NGRAPHS 2000
#define HID 256
#define OUTD 128
#define NCLS 60
#define BN_EPS 1e-5f
#define NROWBLK 1563   // ceil(NNODES/64)
#define NSCANBLK 98    // ceil(NNODES/1024)
#define REDBLK 32
// atomic-free CSR build geometry
#define CHUNK 16384            // nodes per LDS histogram chunk (power of 2)
#define NCHUNK 7               // 7*16384 = 114688 >= NNODES
#define NSLICE 32              // edge slices
#define ESLICE 50000           // NEDGES / NSLICE

typedef __attribute__((ext_vector_type(8))) short bf16x8;
typedef __attribute__((ext_vector_type(4))) float f32x4;

__device__ __forceinline__ float b2f(unsigned short b) {
    unsigned int u = ((unsigned int)b) << 16;
    return __builtin_bit_cast(float, u);
}
__device__ __forceinline__ unsigned short f2b(float f) {
    unsigned int u = __builtin_bit_cast(unsigned int, f);
    u = (u + 0x7FFFu + ((u >> 16) & 1u)) >> 16;     // RNE
    return (unsigned short)u;
}

// ---------------- chunked LDS histograms: NO global atomics ----------------
// blocks [0, 224): dst-table (c = b/32, s = b%32), records lrank[e]
// blocks [224,448): src-table counts only
__global__ __launch_bounds__(256) void k_hist(
        const int* __restrict__ src, const int* __restrict__ dst,
        int* __restrict__ partialD, int* __restrict__ partialS,
        int* __restrict__ lrank) {
    __shared__ int h[CHUNK];
    int bid = blockIdx.x;
    bool isD = bid < NCHUNK * NSLICE;
    int id = isD ? bid : bid - NCHUNK * NSLICE;
    int c = id / NSLICE, s = id % NSLICE;
    int tid = threadIdx.x;
    for (int i = tid; i < CHUNK; i += 256) h[i] = 0;
    __syncthreads();
    int e0 = s * ESLICE;
    int lo = c * CHUNK;
    if (isD) {
#pragma unroll 4
        for (int e = e0 + tid; e < e0 + ESLICE; e += 256) {
            int d = dst[e];
            unsigned int b = (unsigned int)(d - lo);
            if (b < CHUNK) lrank[e] = atomicAdd(&h[b], 1);
        }
    } else {
#pragma unroll 4
        for (int e = e0 + tid; e < e0 + ESLICE; e += 256) {
            int d = src[e];
            unsigned int b = (unsigned int)(d - lo);
            if (b < CHUNK) atomicAdd(&h[b], 1);
        }
    }
    __syncthreads();
    int* out = (isD ? partialD : partialS) + ((size_t)c * NSLICE + s) * CHUNK;
    for (int i = tid; i < CHUNK; i += 256) out[i] = h[i];
}

// ---------------- per-node slice prefix (in place) + degrees + isqrt ----------------
__global__ __launch_bounds__(256) void k_sprefix(
        int* __restrict__ partialD, const int* __restrict__ partialS,
        int* __restrict__ din, float* __restrict__ dos, float* __restrict__ dis) {
    int g = blockIdx.x * 256 + threadIdx.x;    // g in [0, NCHUNK*CHUNK) == node id
    int c = g >> 14, bin = g & (CHUNK - 1);
    int acc = 0;
#pragma unroll 4
    for (int s = 0; s < NSLICE; ++s) {
        size_t idx = ((size_t)c * NSLICE + s) * CHUNK + bin;
        int v = partialD[idx];
        partialD[idx] = acc;                   // exclusive prefix over slices
        acc += v;
    }
    int so = 0;
#pragma unroll 4
    for (int s = 0; s < NSLICE; ++s)
        so += partialS[((size_t)c * NSLICE + s) * CHUNK + bin];
    if (g < NNODES) {
        din[g] = acc;
        dos[g] = so > 0 ? rsqrtf((float)so) : 0.f;
        dis[g] = acc > 0 ? rsqrtf((float)acc) : 0.f;
    }
}

// ---------------- hierarchical exclusive scan of din -> row_ptr ----------
__global__ void k_blk_sum(const int* __restrict__ din, int* __restrict__ bsum) {
    __shared__ int red[256];
    int blk = blockIdx.x, tid = threadIdx.x;
    int base = blk * 1024;
    int s = 0;
#pragma unroll
    for (int j = 0; j < 4; ++j) {
        int i = base + tid + j * 256;
        if (i < NNODES) s += din[i];
    }
    red[tid] = s;
    __syncthreads();
    for (int off = 128; off > 0; off >>= 1) {
        if (tid < off) red[tid] += red[tid + off];
        __syncthreads();
    }
    if (tid == 0) bsum[blk] = red[0];
}

__global__ void k_scan_bsum(int* __restrict__ bsum) {
    if (threadIdx.x == 0) {
        int acc = 0;
        for (int i = 0; i < NSCANBLK; ++i) { int v = bsum[i]; bsum[i] = acc; acc += v; }
    }
}

__global__ void k_scan_local(const int* __restrict__ deg, const int* __restrict__ bsum,
                             int* __restrict__ row_ptr) {
    __shared__ int buf[1024];
    int blk = blockIdx.x, tid = threadIdx.x;
    int i = blk * 1024 + tid;
    int v = (i < NNODES) ? deg[i] : 0;
    buf[tid] = v;
    __syncthreads();
    for (int off = 1; off < 1024; off <<= 1) {
        int t = (tid >= off) ? buf[tid - off] : 0;
        __syncthreads();
        buf[tid] += t;
        __syncthreads();
    }
    int inc = buf[tid] + bsum[blk];
    if (i < NNODES) row_ptr[i + 1] = inc;
    if (i == 0) row_ptr[0] = 0;
}

// ---------------- atomic-free edge placement ----------------
__global__ __launch_bounds__(256) void k_place(
        const int* __restrict__ src, const int* __restrict__ dst,
        const int* __restrict__ lrank, const int* __restrict__ row_ptr,
        const int* __restrict__ partialD, int* __restrict__ csr_e) {
    int e = blockIdx.x * 256 + threadIdx.x;
    if (e >= NEDGES) return;
    int d = dst[e];
    int s = e / ESLICE;
    int c = d >> 14, bin = d & (CHUNK - 1);
    int pos = row_ptr[d] + partialD[((size_t)c * NSLICE + s) * CHUNK + bin] + lrank[e];
    csr_e[pos] = src[e];
}

// ---------------- fused prep: nf7 | weight-convert x3 | M1/v1 ----------------------
__global__ void k_prep(const float* __restrict__ nf, const float* __restrict__ dos,
                       float* __restrict__ nf7,
                       const float* __restrict__ W2, const float* __restrict__ Wc2,
                       const float* __restrict__ W3, unsigned short* __restrict__ Wt2,
                       unsigned short* __restrict__ Wtc2, unsigned short* __restrict__ Wt3,
                       const float* __restrict__ Wemb, const float* __restrict__ bemb,
                       const float* __restrict__ Wc1, float* __restrict__ M1,
                       float* __restrict__ v1) {
    int blk = blockIdx.x, tid = threadIdx.x;
    if (blk < 391) {
        int n = blk * 256 + tid;
        if (n < NNODES) {
            float w = dos[n];
            const float* p = nf + (size_t)n * 6;
            float4 lo = {p[0] * w, p[1] * w, p[2] * w, p[3] * w};
            float4 hi = {p[4] * w, p[5] * w, w, 0.f};
            float4* o = (float4*)(nf7 + (size_t)n * 8);
            o[0] = lo; o[1] = hi;
        }
    } else if (blk < 1031) {
        int idx = (blk - 391) * 256 + tid;
        if (idx < 65536) {
            int n = idx >> 8, k = idx & 255;
            Wt2[idx] = f2b(W2[k * 256 + n]);
        } else if (idx < 131072) {
            int j = idx - 65536;
            int n = j >> 8, k = j & 255;
            Wtc2[j] = f2b(Wc2[k * 256 + n]);
        } else {
            int j = idx - 131072;
            int n = j >> 8, k = j & 255;
            Wt3[j] = f2b(W3[k * 128 + n]);
        }
    } else {
        int bi = blk - 1031;
        int c = tid;
        float acc = 0.f;
        if (bi < 6) {
            for (int k = 0; k < HID; ++k) acc = fmaf(Wemb[bi * HID + k], Wc1[k * HID + c], acc);
            M1[bi * HID + c] = acc;
        } else {
            for (int k = 0; k < HID; ++k) acc = fmaf(bemb[k], Wc1[k * HID + c], acc);
            v1[c] = acc;
        }
    }
}

// ---------------- 7-dim edge aggregation (collapsed layer-1 conv, pre-scaled) -------
__global__ void k_agg6(const int* __restrict__ row_ptr, const int* __restrict__ csr_e,
                       const float* __restrict__ nf7, float* __restrict__ t7) {
    int n = blockIdx.x * blockDim.x + threadIdx.x;
    if (n >= NNODES) return;
    float a0 = 0, a1 = 0, a2 = 0, a3 = 0, a4 = 0, a5 = 0, a6 = 0;
    int s = row_ptr[n], e = row_ptr[n + 1];
    int i = s;
    for (; i + 2 <= e; i += 2) {
        const float4* p0 = (const float4*)(nf7 + (size_t)csr_e[i] * 8);
        const float4* p1 = (const float4*)(nf7 + (size_t)csr_e[i + 1] * 8);
        float4 l0 = p0[0], h0 = p0[1], l1 = p1[0], h1 = p1[1];
        a0 += l0.x; a1 += l0.y; a2 += l0.z; a3 += l0.w; a4 += h0.x; a5 += h0.y; a6 += h0.z;
        a0 += l1.x; a1 += l1.y; a2 += l1.z; a3 += l1.w; a4 += h1.x; a5 += h1.y; a6 += h1.z;
    }
    if (i < e) {
        const float4* p0 = (const float4*)(nf7 + (size_t)csr_e[i] * 8);
        float4 l0 = p0[0], h0 = p0[1];
        a0 += l0.x; a1 += l0.y; a2 += l0.z; a3 += l0.w; a4 += h0.x; a5 += h0.y; a6 += h0.z;
    }
    float4* o = (float4*)(t7 + (size_t)n * 8);
    o[0] = make_float4(a0, a1, a2, a3);
    o[1] = make_float4(a4, a5, a6, 0.f);
}

// ---------------- fused layer 1 -> bf16 h_pre1 + fp32 BN partials ----------------
__global__ __launch_bounds__(256) void k_layer1(
    const float* __restrict__ nf, const float* __restrict__ Wemb, const float* __restrict__ bemb,
    const float* __restrict__ M1, const float* __restrict__ v1, const float* __restrict__ bc1,
    const float* __restrict__ t7, const float* __restrict__ dis,
    unsigned short* __restrict__ H, float* __restrict__ psum, float* __restrict__ psq) {
    __shared__ float s_nf[64][6];
    __shared__ float s_t7[64][8];
    __shared__ float s_r[64];
    int blk = blockIdx.x;
    int n0 = blk * 64;
    int tid = threadIdx.x;
    for (int t = tid; t < 384; t += 256) {
        int nl = t / 6, i = t % 6;
        int n = n0 + nl;
        s_nf[nl][i] = (n < NNODES) ? nf[(size_t)n * 6 + i] : 0.f;
    }
    if (tid < 128) {   // 64 rows x 8 floats = 128 float4; guard to NNODES rows
        int n = n0 + tid / 2;
        if (n < NNODES)
            ((float4*)s_t7)[tid] = ((const float4*)(t7 + (size_t)n0 * 8))[tid];
        else
            ((float4*)s_t7)[tid] = make_float4(0.f, 0.f, 0.f, 0.f);
    }
    if (tid < 64) {
        int n = n0 + tid;
        s_r[tid] = (n < NNODES) ? dis[n] : 0.f;
    }
    int c = tid;
    float wc[6], mc[6];
#pragma unroll
    for (int i = 0; i < 6; ++i) { wc[i] = Wemb[i * HID + c]; mc[i] = M1[i * HID + c]; }
    float v1c = v1[c];
    float bsum = bemb[c] + bc1[c];
    __syncthreads();
    float ps = 0.f, pq = 0.f;
    int nmax = min(64, NNODES - n0);
    for (int nl = 0; nl < nmax; ++nl) {
        float nfd = 0.f, td = 0.f;
#pragma unroll
        for (int i = 0; i < 6; ++i) {
            nfd = fmaf(s_nf[nl][i], wc[i], nfd);
            td = fmaf(s_t7[nl][i], mc[i], td);
        }
        float val = nfd + s_r[nl] * (td + s_t7[nl][6] * v1c) + bsum;
        H[(size_t)(n0 + nl) * HID + c] = f2b(val);
        ps += val;
        pq = fmaf(val, val, pq);
    }
    for (int nl = nmax; nl < 64; ++nl) H[(size_t)(n0 + nl) * HID + c] = 0;  // zero pad rows
    psum[blk * HID + c] = ps;
    psq[blk * HID + c] = pq;
}

// ---------------- BN two-stage reduce -> scale/shift ----------------
__global__ void k_bn_part(const float* __restrict__ psum, const float* __restrict__ psq,
                          double* __restrict__ tmp) {
    int c = threadIdx.x;
    int s = blockIdx.x;
    double a = 0.0, b = 0.0;
    for (int bb = s; bb < NROWBLK; bb += REDBLK) {
        a += psum[bb * HID + c];
        b += psq[bb * HID + c];
    }
    tmp[s * HID + c] = a;
    tmp[(REDBLK + s) * HID + c] = b;
}

__global__ void k_bn_final(const double* __restrict__ tmp, const float* __restrict__ g,
                           const float* __restrict__ be, float* __restrict__ scale,
                           float* __restrict__ shift) {
    int c = threadIdx.x;
    double s = 0.0, q = 0.0;
    for (int i = 0; i < REDBLK; ++i) { s += tmp[i * HID + c]; q += tmp[(REDBLK + i) * HID + c]; }
    double mu = s / (double)NNODES;
    double var = q / (double)NNODES - mu * mu;
    if (var < 0.0) var = 0.0;
    double inv = 1.0 / sqrt(var + (double)BN_EPS);
    float sc = (float)((double)g[c] * inv);
    scale[c] = sc;
    shift[c] = be[c] - (float)mu * sc;
}

// ================= bf16 MFMA GEMM, A-panel reused across all column blocks =========
// RS: multiply output rows by rs[row] (folds dout^-1/2 into h2 for the gather pass)
template <int NC, bool ATRANS, bool XEPI, bool PART, bool OUTF32, bool RS>
__global__ __launch_bounds__(256, 2) void k_mgemm(
    const unsigned short* __restrict__ A, const unsigned short* __restrict__ Bt,
    const float* __restrict__ bias,
    const float* __restrict__ scale, const float* __restrict__ shift,
    const float* __restrict__ nf, const float* __restrict__ Wemb, const float* __restrict__ bemb,
    const float* __restrict__ rs,
    unsigned short* __restrict__ Cb, float* __restrict__ Cf,
    float* __restrict__ psum, float* __restrict__ psq) {
    __shared__ unsigned short As[64 * 256];
    __shared__ unsigned short Bs[64 * 256];
    __shared__ float sSc[HID];
    __shared__ float sSh[HID];
    __shared__ float sNf[64][6];
    __shared__ float sXW[6][HID];
    __shared__ float sRs[64];
    __shared__ float redS[2][64];
    __shared__ float redQ[2][64];

    int tid = threadIdx.x;
    int rb = blockIdx.x;
    int row0 = rb * 64;

    if (ATRANS) { sSc[tid] = scale[tid]; sSh[tid] = shift[tid]; }
    if (RS && tid < 64) {
        int n = row0 + tid;
        sRs[tid] = (n < NNODES) ? rs[n] : 0.f;
    }
    if (XEPI) {
        for (int t = tid; t < 6 * NC; t += 256) {
            int i = t / NC, cl = t % NC;
            sXW[i][cl] = Wemb[i * HID + cl];
        }
        if (tid < 64) {
            int n = row0 + tid;
#pragma unroll
            for (int i = 0; i < 6; ++i) sNf[tid][i] = (n < NNODES) ? nf[(size_t)n * 6 + i] : 0.f;
        }
    }
    if (ATRANS) __syncthreads();   // sSc/sSh consumed during A staging

    // ---- stage A tile 64x256 bf16 once ----
#pragma unroll
    for (int i = 0; i < 8; ++i) {
        int g = i * 256 + tid;
        int row = g >> 5, kc = g & 31;
        uint4 v = *(const uint4*)(A + (size_t)(row0 + row) * 256 + kc * 8);
        if (ATRANS) {
            unsigned int w[4] = {v.x, v.y, v.z, v.w};
#pragma unroll
            for (int q = 0; q < 4; ++q) {
                int k0 = kc * 8 + q * 2;
                float f0 = b2f((unsigned short)(w[q] & 0xffffu));
                float f1 = b2f((unsigned short)(w[q] >> 16));
                f0 = fmaxf(fmaf(f0, sSc[k0], sSh[k0]), 0.f);
                f1 = fmaxf(fmaf(f1, sSc[k0 + 1], sSh[k0 + 1]), 0.f);
                w[q] = (unsigned int)f2b(f0) | ((unsigned int)f2b(f1) << 16);
            }
            v.x = w[0]; v.y = w[1]; v.z = w[2]; v.w = w[3];
        }
        int pkc = kc ^ (row & 7);
        *(uint4*)(&As[row * 256 + pkc * 8]) = v;
    }

    int w = tid >> 6, lane = tid & 63;
    int wm = w >> 1, wn = w & 1;            // 2x2 wave grid, each wave 32x32
    int lrow = lane & 15, lk = lane >> 4;

    for (int cb = 0; cb < NC / 64; ++cb) {
        int c0 = cb * 64;
        if (cb) __syncthreads();
        // ---- stage B^T tile 64x256 bf16 ----
#pragma unroll
        for (int i = 0; i < 8; ++i) {
            int g = i * 256 + tid;
            int row = g >> 5, kc = g & 31;
            uint4 v = *(const uint4*)(Bt + (size_t)(c0 + row) * 256 + kc * 8);
            int pkc = kc ^ (row & 7);
            *(uint4*)(&Bs[row * 256 + pkc * 8]) = v;
        }
        __syncthreads();

        f32x4 acc[2][2] = {};
#pragma unroll
        for (int ks = 0; ks < 8; ++ks) {
            bf16x8 af[2], bfr[2];
#pragma unroll
            for (int fm = 0; fm < 2; ++fm) {
                int r = wm * 32 + fm * 16 + lrow;
                int kc = ks * 4 + lk;
                af[fm] = *(const bf16x8*)(&As[r * 256 + (kc ^ (r & 7)) * 8]);
            }
#pragma unroll
            for (int fn = 0; fn < 2; ++fn) {
                int r = wn * 32 + fn * 16 + lrow;
                int kc = ks * 4 + lk;
                bfr[fn] = *(const bf16x8*)(&Bs[r * 256 + (kc ^ (r & 7)) * 8]);
            }
#pragma unroll
            for (int fm = 0; fm < 2; ++fm)
#pragma unroll
                for (int fn = 0; fn < 2; ++fn)
                    acc[fm][fn] = __builtin_amdgcn_mfma_f32_16x16x32_bf16(af[fm], bfr[fn], acc[fm][fn], 0, 0, 0);
        }

        // ---- epilogue (C/D layout: col=lane&15, row=(lane>>4)*4+reg) ----
        float pS[2] = {0.f, 0.f}, pQ[2] = {0.f, 0.f};
#pragma unroll
        for (int fn = 0; fn < 2; ++fn) {
            int cl = wn * 32 + fn * 16 + lrow;
            int gc = c0 + cl;
            float bv = bias[gc];
            if (XEPI) bv += bemb[gc];
#pragma unroll
            for (int fm = 0; fm < 2; ++fm) {
#pragma unroll
                for (int r = 0; r < 4; ++r) {
                    int rl = wm * 32 + fm * 16 + lk * 4 + r;
                    int gr = row0 + rl;
                    float val = acc[fm][fn][r] + bv;
                    if (XEPI) {
#pragma unroll
                        for (int l = 0; l < 6; ++l) val = fmaf(sNf[rl][l], sXW[l][gc], val);
                    }
                    if (RS) val *= sRs[rl];
                    if (gr < NNODES) {
                        if (OUTF32) Cf[(size_t)gr * NC + gc] = val;
                        else        Cb[(size_t)gr * NC + gc] = f2b(val);
                        if (PART) { pS[fn] += val; pQ[fn] = fmaf(val, val, pQ[fn]); }
                    }
                }
            }
        }
        if (PART) {
#pragma unroll
            for (int fn = 0; fn < 2; ++fn) {
                float s = pS[fn], q = pQ[fn];
                s += __shfl_xor(s, 16); s += __shfl_xor(s, 32);
                q += __shfl_xor(q, 16); q += __shfl_xor(q, 32);
                if (lk == 0) {
                    int cl = wn * 32 + fn * 16 + lrow;
                    redS[wm][cl] = s;
                    redQ[wm][cl] = q;
                }
            }
            __syncthreads();
            if (tid < 64) {
                psum[(size_t)rb * HID + c0 + tid] = redS[0][tid] + redS[1][tid];
                psq [(size_t)rb * HID + c0 + tid] = redQ[0][tid] + redQ[1][tid];
            }
        }
    }
}

// ---------------- bf16 conv aggregation: weights pre-folded, plain row sums ---------
#define ADD8(vv) { \
    a[0] += b2f((unsigned short)(vv.x & 0xffffu)); \
    a[1] += b2f((unsigned short)(vv.x >> 16)); \
    a[2] += b2f((unsigned short)(vv.y & 0xffffu)); \
    a[3] += b2f((unsigned short)(vv.y >> 16)); \
    a[4] += b2f((unsigned short)(vv.z & 0xffffu)); \
    a[5] += b2f((unsigned short)(vv.z >> 16)); \
    a[6] += b2f((unsigned short)(vv.w & 0xffffu)); \
    a[7] += b2f((unsigned short)(vv.w >> 16)); }

__global__ __launch_bounds__(256) void k_agg(const int* __restrict__ row_ptr,
                                             const int* __restrict__ csr_e,
                                             const unsigned short* __restrict__ X,
                                             const float* __restrict__ dis,
                                             unsigned short* __restrict__ out) {
    int wid = threadIdx.x >> 6, lane = threadIdx.x & 63;
    int half = lane >> 5, l32 = lane & 31;
    int n = blockIdx.x * 4 + wid;
    if (n >= NNODES) return;
    int s = row_ptr[n], e = row_ptr[n + 1];
    float a[8] = {0.f, 0.f, 0.f, 0.f, 0.f, 0.f, 0.f, 0.f};
    int i = s;
    for (; i + 8 <= e; i += 8) {
        int s0 = csr_e[i + half];
        int s1 = csr_e[i + 2 + half];
        int s2 = csr_e[i + 4 + half];
        int s3 = csr_e[i + 6 + half];
        uint4 v0 = ((const uint4*)(X + (size_t)s0 * HID))[l32];
        uint4 v1 = ((const uint4*)(X + (size_t)s1 * HID))[l32];
        uint4 v2 = ((const uint4*)(X + (size_t)s2 * HID))[l32];
        uint4 v3 = ((const uint4*)(X + (size_t)s3 * HID))[l32];
        ADD8(v0) ADD8(v1) ADD8(v2) ADD8(v3)
    }
    for (; i + 2 <= e; i += 2) {
        int s0 = csr_e[i + half];
        uint4 v0 = ((const uint4*)(X + (size_t)s0 * HID))[l32];
        ADD8(v0)
    }
    if (i < e && half == 0) {       // odd leftover edge: half 0 only
        int s0 = csr_e[i];
        uint4 v0 = ((const uint4*)(X + (size_t)s0 * HID))[l32];
        ADD8(v0)
    }
#pragma unroll
    for (int j = 0; j < 8; ++j) a[j] += __shfl_xor(a[j], 32);
    if (half == 0) {
        float r = dis[n];
        uint4 o;
        o.x = (unsigned)f2b(a[0] * r) | ((unsigned)f2b(a[1] * r) << 16);
        o.y = (unsigned)f2b(a[2] * r) | ((unsigned)f2b(a[3] * r) << 16);
        o.z = (unsigned)f2b(a[4] * r) | ((unsigned)f2b(a[5] * r) << 16);
        o.w = (unsigned)f2b(a[6] * r) | ((unsigned)f2b(a[7] * r) << 16);
        ((uint4*)(out + (size_t)n * HID))[l32] = o;
    }
}

// ---------------- graph mean (sorted graph_ids, binary search) + classifier --------
__global__ __launch_bounds__(128) void k_mean_label(const float* __restrict__ Hout,
                                                    const int* __restrict__ gids,
                                                    const float* __restrict__ Wcls,
                                                    const float* __restrict__ bcls,
                                                    float* __restrict__ lab) {
    int g = blockIdx.x;
    int c = threadIdx.x;
    int lo = 0, hi = NNODES;
    while (lo < hi) { int mid = (lo + hi) >> 1; if (gids[mid] < g) lo = mid + 1; else hi = mid; }
    int s = lo;
    hi = NNODES;
    while (lo < hi) { int mid = (lo + hi) >> 1; if (gids[mid] < g + 1) lo = mid + 1; else hi = mid; }
    int e = lo;
    float acc = 0.f;
    for (int n = s; n < e; ++n) acc += Hout[(size_t)n * OUTD + c];
    int cnt = e - s;
    float y = acc / (float)max(cnt, 1);
    __shared__ float ys[OUTD];
    ys[c] = y;
    __syncthreads();
    if (c < NCLS) {
        float a = bcls[c];
        for (int k = 0; k < OUTD; ++k) a = fmaf(ys[k], Wcls[k * NCLS + c], a);
        lab[(size_t)g * NCLS + c] = a;
    }
}

// ---------------- host ----------------
extern "C" void kernel_launch(void* const* d_in, const int* in_sizes, int n_in,
                              void* d_out, int out_size, void* d_ws, size_t ws_size,
                              hipStream_t stream) {
    const float* nf   = (const float*)d_in[0];
    const int*   src  = (const int*)d_in[1];
    const int*   dst  = (const int*)d_in[2];
    const int*   gids = (const int*)d_in[3];
    const float* Wemb = (const float*)d_in[4];
    const float* bemb = (const float*)d_in[5];
    const float* Wc1  = (const float*)d_in[6];
    const float* bc1  = (const float*)d_in[7];
    const float* g1   = (const float*)d_in[8];
    const float* be1  = (const float*)d_in[9];
    const float* W2   = (const float*)d_in[10];
    const float* b2   = (const float*)d_in[11];
    const float* Wc2  = (const float*)d_in[12];
    const float* bc2  = (const float*)d_in[13];
    const float* g2   = (const float*)d_in[14];
    const float* be2  = (const float*)d_in[15];
    const float* W3   = (const float*)d_in[16];
    const float* b3   = (const float*)d_in[17];
    const float* Wcls = (const float*)d_in[18];
    const float* bcls = (const float*)d_in[19];

    float* out_h   = (float*)d_out;                 // [N, 128] fp32
    float* out_lab = out_h + (size_t)NNODES * OUTD; // [G, 60]

    // workspace bump allocator (floats, 256B granularity)
    float* ws = (float*)d_ws;
    size_t off = 0;
    auto take = [&](size_t n) { float* p = ws + off; off += (n + 63) & ~(size_t)63; return p; };
    unsigned short* actA = (unsigned short*)take((size_t)MPAD * HID / 2);  // bf16 [MPAD][256]
    unsigned short* actB = (unsigned short*)take((size_t)MPAD * HID / 2);  // bf16 [MPAD][256]
    unsigned short* Wt2  = (unsigned short*)take(HID * HID / 2);
    unsigned short* Wtc2 = (unsigned short*)take(HID * HID / 2);
    unsigned short* Wt3  = (unsigned short*)take(OUTD * HID / 2);
    float* dout_is = take(NNODES);                 // dos
    float* din_is  = take(NNODES);                 // dis
    int*   row_ptr = (int*)take(NNODES + 1);
    int*   din     = (int*)take(NNODES);
    int*   csr_e   = (int*)take(NEDGES);
    float* t7      = take((size_t)MPAD * 8);
    float* nf7_ps  = take(800320);                 // nf7 (prep/agg6), then psum+psq
    float* M1      = take(6 * HID);
    float* v1      = take(HID);
    float* scale1  = take(HID);
    float* shift1  = take(HID);
    float* scale2  = take(HID);
    float* shift2  = take(HID);
    int*   bsum    = (int*)take(128);
    double* bn_tmp = (double*)take(2 * 2 * REDBLK * HID);

    // aliases (lifetimes: partials/lrank dead after k_place; actA first written at
    // k_layer1, actB at k_mgemm step 9 — both strictly later)
    int*   partialD = (int*)actA;                          // 7*32*16384 ints = 14.68MB
    int*   partialS = partialD + (size_t)NCHUNK * NSLICE * CHUNK;
    int*   lrank    = (int*)actB;                          // 6.4MB
    float* nf7      = nf7_ps;
    float* psum     = nf7_ps;
    float* psq      = nf7_ps + 400128;

    // 1. chunked LDS histograms (src & dst) + per-edge slice-local ranks. NO atomics
    //    to global memory anywhere in the CSR build.
    k_hist<<<2 * NCHUNK * NSLICE, 256, 0, stream>>>(src, dst, partialD, partialS, lrank);
    // 2. slice-prefix (in place) + din + dos/dis
    k_sprefix<<<NCHUNK * CHUNK / 256, 256, 0, stream>>>(partialD, partialS, din,
                                                        dout_is, din_is);
    // 3. hierarchical scan din -> row_ptr
    k_blk_sum<<<NSCANBLK, 256, 0, stream>>>(din, bsum);
    k_scan_bsum<<<1, 64, 0, stream>>>(bsum);
    k_scan_local<<<NSCANBLK, 1024, 0, stream>>>(din, bsum, row_ptr);
    // 4. atomic-free placement
    k_place<<<(NEDGES + 255) / 256, 256, 0, stream>>>(src, dst, lrank, row_ptr,
                                                      partialD, csr_e);
    // 5. fused prep: nf7 + weight converts + M1/v1
    k_prep<<<1038, 256, 0, stream>>>(nf, dout_is, nf7, W2, Wc2, W3, Wt2, Wtc2, Wt3,
                                     Wemb, bemb, Wc1, M1, v1);
    // 6. 7-dim aggregation -> t7
    k_agg6<<<(NNODES + 255) / 256, 256, 0, stream>>>(row_ptr, csr_e, nf7, t7);
    // 7. fused layer 1 -> actA (h_pre1 bf16) + BN1 partials (psum/psq overwrite nf7)
    k_layer1<<<NROWBLK, 256, 0, stream>>>(nf, Wemb, bemb, M1, v1, bc1, t7, din_is,
                                          actA, psum, psq);
    // 8. BN1 scale/shift
    k_bn_part<<<REDBLK, 256, 0, stream>>>(psum, psq, bn_tmp);
    k_bn_final<<<1, 256, 0, stream>>>(bn_tmp, g1, be1, scale1, shift1);
    // 9. h2 = (relu(bn1(h_pre1)) @ W2 + b2) * dout^-1/2[row] -> actB (bf16)
    k_mgemm<HID, true, false, false, false, true><<<NROWBLK, 256, 0, stream>>>(
        actA, Wt2, b2, scale1, shift1, nullptr, nullptr, nullptr, dout_is,
        actB, nullptr, nullptr, nullptr);
    // 10. A2 = dis * row-sum gather of actB -> actA (bf16)
    k_agg<<<NNODES / 4, 256, 0, stream>>>(row_ptr, csr_e, actB, din_is, actA);
    // 11. h_pre2 = x + A2 @ Wc2 + bc2 -> actB (bf16) + BN2 partials
    k_mgemm<HID, false, true, true, false, false><<<NROWBLK, 256, 0, stream>>>(
        actA, Wtc2, bc2, nullptr, nullptr, nf, Wemb, bemb, nullptr,
        actB, nullptr, psum, psq);
    // 12. BN2 scale/shift
    k_bn_part<<<REDBLK, 256, 0, stream>>>(psum, psq, bn_tmp);
    k_bn_final<<<1, 256, 0, stream>>>(bn_tmp, g2, be2, scale2, shift2);
    // 13. h_out = relu(bn2(h_pre2)) @ W3 + b3 -> d_out fp32
    k_mgemm<OUTD, true, false, false, true, false><<<NROWBLK, 256, 0, stream>>>(
        actB, Wt3, b3, scale2, shift2, nullptr, nullptr, nullptr, nullptr,
        nullptr, out_h, nullptr, nullptr);
    // 14. graph mean + classifier
    k_mean_label<<<NGRAPHS, OUTD, 0, stream>>>(out_h, gids, Wcls, bcls, out_lab);
}